// Round 1
// baseline (988.991 us; speedup 1.0000x reference)
//
#include <hip/hip_runtime.h>
#include <hip/hip_bf16.h>
#include <cstdint>
#include <cstddef>

#define N_  8
#define C_  256
#define HW_ 1024
#define CL_ 16
#define SZ_ (N_*C_*HW_)   // 2,097,152 floats per tensor

static __device__ __forceinline__ float tanh_fast(float x){
  x = fminf(fmaxf(x, -15.f), 15.f);
  float e = __expf(2.f * x);
  return (e - 1.f) / (e + 1.f);
}

// K1a: cval[n,side,hw] = sum_c f[c,hw]*cw[c];  pdot[n,side,l,hw] = sum_c f[c,hw]*pw[l,c]
// grid (16, 2, 8), block 256. threads: hwl = t&63, cgroup = t>>6 (64 channels each)
__global__ __launch_bounds__(256) void k_sa_dot(
    const float* __restrict__ fp1, const float* __restrict__ fp2,
    const float* __restrict__ cw1, const float* __restrict__ cw2,
    const float* __restrict__ pw1, const float* __restrict__ pw2,
    float* __restrict__ cval, float* __restrict__ pdot)
{
  const int n = blockIdx.z, side = blockIdx.y, hw0 = blockIdx.x * 64;
  const int t = threadIdx.x, hwl = t & 63, cg = t >> 6;
  const float* __restrict__ pw = side ? pw2 : pw1;
  const float* __restrict__ cw = side ? cw2 : cw1;
  const float* __restrict__ f  = (side ? fp2 : fp1) + (size_t)n * C_ * HW_ + hw0 + hwl;
  // wave-uniform channel base -> scalar loads for coefficients
  const int cb = __builtin_amdgcn_readfirstlane(cg * 64);

  float acc[17];
  #pragma unroll
  for (int l = 0; l < 17; ++l) acc[l] = 0.f;

  for (int cc = 0; cc < 64; ++cc){
    const int c = cb + cc;
    const float v = f[(size_t)c * HW_];
    acc[16] += v * cw[c];
    #pragma unroll
    for (int l = 0; l < 16; ++l) acc[l] += v * pw[l * C_ + c];
  }

  __shared__ float red[17][4][64];
  #pragma unroll
  for (int l = 0; l < 17; ++l) red[l][cg][hwl] = acc[l];
  __syncthreads();

  if (t < 64){
    const int base = n * 2 + side;
    #pragma unroll
    for (int l = 0; l < 17; ++l){
      const float s = red[l][0][t] + red[l][1][t] + red[l][2][t] + red[l][3][t];
      if (l < 16) pdot[((size_t)base * CL_ + l) * HW_ + hw0 + t] = s;
      else        cval[(size_t)base * HW_ + hw0 + t] = s;
    }
  }
}

// K1b: softmax over HW (per n,side) -> wbuf; fcl = w*pdot + pb
// grid (2, 8), block 1024
__global__ __launch_bounds__(1024) void k_softmax_fcl(
    const float* __restrict__ cval, const float* __restrict__ pdot,
    const float* __restrict__ cb1, const float* __restrict__ cb2,
    const float* __restrict__ pb1, const float* __restrict__ pb2,
    float* __restrict__ wbuf, float* __restrict__ fcl)
{
  const int side = blockIdx.x, n = blockIdx.y, t = threadIdx.x;
  const int base = n * 2 + side;
  __shared__ float arr[1024];

  const float x = cval[(size_t)base * HW_ + t] + (side ? cb2[0] : cb1[0]);
  arr[t] = x; __syncthreads();
  for (int s = 512; s > 0; s >>= 1){ if (t < s) arr[t] = fmaxf(arr[t], arr[t + s]); __syncthreads(); }
  const float m = arr[0]; __syncthreads();

  const float e = __expf(x - m);
  arr[t] = e; __syncthreads();
  for (int s = 512; s > 0; s >>= 1){ if (t < s) arr[t] += arr[t + s]; __syncthreads(); }
  const float wv = e / arr[0];

  wbuf[(size_t)base * HW_ + t] = wv;
  const float* __restrict__ pb = side ? pb2 : pb1;
  #pragma unroll
  for (int l = 0; l < 16; ++l){
    const size_t pi = ((size_t)base * CL_ + l) * HW_ + t;
    fcl[pi] = wv * pdot[pi] + pb[l];
  }
}

// K2: A[n,i,j] = tanh( sum_l f2cl[l,i] * f1cl[l,j] ).  64x64 tile per block.
// grid (16 jtiles, 16 itiles, 8), block 256 (16x16 threads, 4x4 micro)
__global__ __launch_bounds__(256) void k_corr(const float* __restrict__ fcl, float* __restrict__ Abuf)
{
  const int n = blockIdx.z, i0 = blockIdx.y * 64, j0 = blockIdx.x * 64;
  const float* __restrict__ f1c = fcl + (size_t)(n * 2 + 0) * CL_ * HW_;
  const float* __restrict__ f2c = fcl + (size_t)(n * 2 + 1) * CL_ * HW_;
  __align__(16) __shared__ float s2[CL_][64];
  __align__(16) __shared__ float s1[CL_][64];
  const int t = threadIdx.x;
  const int lr = t >> 4, lc = (t & 15) * 4;
  *(float4*)&s2[lr][lc] = *(const float4*)&f2c[(size_t)lr * HW_ + i0 + lc];
  *(float4*)&s1[lr][lc] = *(const float4*)&f1c[(size_t)lr * HW_ + j0 + lc];
  __syncthreads();

  const int ti = t >> 4, tj = t & 15;
  float acc[4][4];
  #pragma unroll
  for (int a = 0; a < 4; ++a)
    #pragma unroll
    for (int b = 0; b < 4; ++b) acc[a][b] = 0.f;

  #pragma unroll
  for (int l = 0; l < CL_; ++l){
    const float4 a4 = *(const float4*)&s2[l][ti * 4];
    const float4 b4 = *(const float4*)&s1[l][tj * 4];
    const float av[4] = {a4.x, a4.y, a4.z, a4.w};
    const float bv[4] = {b4.x, b4.y, b4.z, b4.w};
    #pragma unroll
    for (int a = 0; a < 4; ++a)
      #pragma unroll
      for (int b = 0; b < 4; ++b) acc[a][b] += av[a] * bv[b];
  }

  float* __restrict__ An = Abuf + ((size_t)n << 20);
  #pragma unroll
  for (int a = 0; a < 4; ++a){
    float4 v;
    v.x = tanh_fast(acc[a][0]); v.y = tanh_fast(acc[a][1]);
    v.z = tanh_fast(acc[a][2]); v.w = tanh_fast(acc[a][3]);
    *(float4*)&An[(size_t)(i0 + ti * 4 + a) * HW_ + j0 + tj * 4] = v;
  }
}

// K3: dual GEMM.  g=0: hat1[c,i] = sum_j (w1[j]*f1[c,j]) * A[i,j]
//                 g=1: hat2[c,i] = sum_j (w2[j]*f2[c,j]) * A[j,i]
// BM=64 (c), BN=128 (i), BK=32; 256 threads, 4x8 micro. grid (32, 2, 8).
#define BK_ 32
__global__ __launch_bounds__(256) void k_gemm(
    const float* __restrict__ fp1, const float* __restrict__ fp2,
    const float* __restrict__ wbuf, const float* __restrict__ Abuf,
    float* __restrict__ out)
{
  const int n = blockIdx.z, g = blockIdx.y, tb = blockIdx.x;
  const int c0 = (tb >> 3) * 64, i0 = (tb & 7) * 128;
  const float* __restrict__ X    = (g ? fp2 : fp1) + (size_t)n * C_ * HW_;
  const float* __restrict__ wrow = wbuf + (size_t)(n * 2 + g) * HW_;
  const float* __restrict__ An   = Abuf + ((size_t)n << 20);
  float* __restrict__ outp = out + (size_t)g * SZ_ + (size_t)n * C_ * HW_;

  __align__(16) __shared__ float Xs[BK_][68];    // [k][m], padded
  __align__(16) __shared__ float As[BK_][132];   // [k][nn], padded

  const int t = threadIdx.x;
  const int tm = t >> 4, tn = t & 15;

  float acc[4][8];
  #pragma unroll
  for (int a = 0; a < 4; ++a)
    #pragma unroll
    for (int b = 0; b < 8; ++b) acc[a][b] = 0.f;

  for (int j0 = 0; j0 < HW_; j0 += BK_){
    // X tile: 64 rows (c) x 32 cols (j) -> transposed into Xs[k][m], scaled by w[j]
    #pragma unroll
    for (int itl = 0; itl < 2; ++itl){
      const int idx = t + itl * 256, row = idx >> 3, kc = (idx & 7) * 4;
      float4 v = *(const float4*)&X[(size_t)(c0 + row) * HW_ + j0 + kc];
      const float4 wv = *(const float4*)&wrow[j0 + kc];
      Xs[kc + 0][row] = v.x * wv.x;
      Xs[kc + 1][row] = v.y * wv.y;
      Xs[kc + 2][row] = v.z * wv.z;
      Xs[kc + 3][row] = v.w * wv.w;
    }
    if (g == 0){
      // A[i0+row][j0+kc] -> As[k][row] (transpose)
      #pragma unroll
      for (int itl = 0; itl < 4; ++itl){
        const int idx = t + itl * 256, row = idx >> 3, kc = (idx & 7) * 4;
        const float4 v = *(const float4*)&An[(size_t)(i0 + row) * HW_ + j0 + kc];
        As[kc + 0][row] = v.x; As[kc + 1][row] = v.y;
        As[kc + 2][row] = v.z; As[kc + 3][row] = v.w;
      }
    } else {
      // A[j0+row][i0+col] -> As[row][col] (direct)
      #pragma unroll
      for (int itl = 0; itl < 4; ++itl){
        const int idx = t + itl * 256, row = idx >> 5, col = (idx & 31) * 4;
        *(float4*)&As[row][col] = *(const float4*)&An[(size_t)(j0 + row) * HW_ + i0 + col];
      }
    }
    __syncthreads();

    #pragma unroll 8
    for (int k = 0; k < BK_; ++k){
      const float4 a4 = *(const float4*)&Xs[k][tm * 4];
      const float4 b4 = *(const float4*)&As[k][tn * 8];
      const float4 b5 = *(const float4*)&As[k][tn * 8 + 4];
      const float av[4] = {a4.x, a4.y, a4.z, a4.w};
      const float bv[8] = {b4.x, b4.y, b4.z, b4.w, b5.x, b5.y, b5.z, b5.w};
      #pragma unroll
      for (int a = 0; a < 4; ++a)
        #pragma unroll
        for (int b = 0; b < 8; ++b) acc[a][b] += av[a] * bv[b];
    }
    __syncthreads();
  }

  #pragma unroll
  for (int a = 0; a < 4; ++a){
    float4 v0, v1;
    v0.x = acc[a][0]; v0.y = acc[a][1]; v0.z = acc[a][2]; v0.w = acc[a][3];
    v1.x = acc[a][4]; v1.y = acc[a][5]; v1.z = acc[a][6]; v1.w = acc[a][7];
    *(float4*)&outp[(size_t)(c0 + tm * 4 + a) * HW_ + i0 + tn * 8] = v0;
    *(float4*)&outp[(size_t)(c0 + tm * 4 + a) * HW_ + i0 + tn * 8 + 4] = v1;
  }
}

// K4: h = hat / max(||hat||_c, eps)  (in-place on d_out);  fp = relu(h + fp_in) unless last
// grid (16, 2, 8), block 256
__global__ __launch_bounds__(256) void k_norm_update(
    float* __restrict__ out,
    const float* __restrict__ fpin1, const float* __restrict__ fpin2,
    float* __restrict__ fpo1, float* __restrict__ fpo2, int last)
{
  const int n = blockIdx.z, side = blockIdx.y, i0 = blockIdx.x * 64;
  float* __restrict__ hat = out + (size_t)side * SZ_ + (size_t)n * C_ * HW_;
  const float* __restrict__ fpin = (side ? fpin2 : fpin1) + (size_t)n * C_ * HW_;
  float* __restrict__ fpo = (side ? fpo2 : fpo1) + (size_t)n * C_ * HW_;
  const int t = threadIdx.x, il = t & 63, cg = t >> 6;

  float ss = 0.f;
  for (int cc = 0; cc < 64; ++cc){
    const float v = hat[(size_t)(cg * 64 + cc) * HW_ + i0 + il];
    ss += v * v;
  }
  __shared__ float red[4][64];
  __shared__ float rinv[64];
  red[cg][il] = ss; __syncthreads();
  if (t < 64){
    const float s = red[0][t] + red[1][t] + red[2][t] + red[3][t];
    rinv[t] = 1.f / fmaxf(sqrtf(s), 1e-12f);
  }
  __syncthreads();
  const float ri = rinv[il];

  for (int cc = 0; cc < 64; ++cc){
    const size_t idx = (size_t)(cg * 64 + cc) * HW_ + i0 + il;
    const float h = hat[idx] * ri;
    hat[idx] = h;
    if (!last){
      const float fv = fpin[idx] + h;
      fpo[idx] = fv > 0.f ? fv : 0.f;
    }
  }
}

// K_s: final-iteration s output: s[n,c,hw] = w[n,side,hw] * fp[n,c,hw]
// grid (2048, 2), block 256, one float4 per thread
__global__ __launch_bounds__(256) void k_s_out(
    const float* __restrict__ fp1, const float* __restrict__ fp2,
    const float* __restrict__ wbuf, float* __restrict__ out)
{
  const int side = blockIdx.y;
  const size_t fo = ((size_t)blockIdx.x * 256 + threadIdx.x) * 4;
  const float* __restrict__ f = side ? fp2 : fp1;
  const int n  = (int)(fo >> 18);       // C_*HW_ = 2^18
  const int hw = (int)(fo & (HW_ - 1));
  const float4 v  = *(const float4*)&f[fo];
  const float4 wv = *(const float4*)&wbuf[(size_t)(n * 2 + side) * HW_ + hw];
  float4 r;
  r.x = v.x * wv.x; r.y = v.y * wv.y; r.z = v.z * wv.z; r.w = v.w * wv.w;
  *(float4*)&out[(size_t)(2 + side) * SZ_ + fo] = r;
}

extern "C" void kernel_launch(void* const* d_in, const int* in_sizes, int n_in,
                              void* d_out, int out_size, void* d_ws, size_t ws_size,
                              hipStream_t stream)
{
  const float* f1  = (const float*)d_in[0];
  const float* f2  = (const float*)d_in[1];
  const float* pw1 = (const float*)d_in[2];
  const float* pb1 = (const float*)d_in[3];
  const float* pw2 = (const float*)d_in[4];
  const float* pb2 = (const float*)d_in[5];
  const float* cw1 = (const float*)d_in[6];
  const float* cb1 = (const float*)d_in[7];
  const float* cw2 = (const float*)d_in[8];
  const float* cb2 = (const float*)d_in[9];
  float* out = (float*)d_out;
  float* ws  = (float*)d_ws;

  // workspace layout (floats): total ~13.14M floats (~52.6 MB)
  float* fp1  = ws;                         // SZ_
  float* fp2  = fp1  + SZ_;                 // SZ_
  float* cval = fp2  + SZ_;                 // N*2*HW
  float* wbuf = cval + N_ * 2 * HW_;        // N*2*HW
  float* pdot = wbuf + N_ * 2 * HW_;        // N*2*CL*HW
  float* fcl  = pdot + N_ * 2 * CL_ * HW_;  // N*2*CL*HW
  float* Abuf = fcl  + N_ * 2 * CL_ * HW_;  // N*HW*HW = 8M floats

  for (int it = 0; it < 5; ++it){
    const float* cur1 = (it == 0) ? f1 : fp1;
    const float* cur2 = (it == 0) ? f2 : fp2;

    k_sa_dot<<<dim3(16, 2, 8), 256, 0, stream>>>(cur1, cur2, cw1, cw2, pw1, pw2, cval, pdot);
    k_softmax_fcl<<<dim3(2, 8), 1024, 0, stream>>>(cval, pdot, cb1, cb2, pb1, pb2, wbuf, fcl);
    if (it == 4)
      k_s_out<<<dim3(SZ_ / 4 / 256, 2), 256, 0, stream>>>(cur1, cur2, wbuf, out);
    k_corr<<<dim3(16, 16, 8), 256, 0, stream>>>(fcl, Abuf);
    k_gemm<<<dim3(32, 2, 8), 256, 0, stream>>>(cur1, cur2, wbuf, Abuf, out);
    k_norm_update<<<dim3(16, 2, 8), 256, 0, stream>>>(out, cur1, cur2, fp1, fp2, (it == 4) ? 1 : 0);
  }
}

// Round 2
// 377.280 us; speedup vs baseline: 2.6214x; 2.6214x over previous
//
#include <hip/hip_runtime.h>
#include <hip/hip_bf16.h>
#include <cstdint>
#include <cstddef>

#define N_  8
#define C_  256
#define HW_ 1024
#define CL_ 16
#define SZ_ (N_*C_*HW_)   // 2,097,152 elements per tensor

typedef __attribute__((ext_vector_type(8))) short short8v;
typedef __attribute__((ext_vector_type(4))) float f32x4;

static __device__ __forceinline__ float tanh_fast(float x){
  x = fminf(fmaxf(x, -15.f), 15.f);
  float e = __expf(2.f * x);
  return (e - 1.f) / (e + 1.f);
}

// f32 -> bf16 bits, round-to-nearest-even
static __device__ __forceinline__ unsigned short f2bf(float x){
  union { float f; uint32_t u; } v; v.f = x;
  uint32_t r = v.u + 0x7FFFu + ((v.u >> 16) & 1u);
  return (unsigned short)(r >> 16);
}

#define GLD16(g, l) __builtin_amdgcn_global_load_lds( \
    (const __attribute__((address_space(1))) void*)(g), \
    (__attribute__((address_space(3))) void*)(l), 16, 0, 0)

// K1a: cval[n,side,hw] = sum_c f[c,hw]*cw[c];  pdot[n,side,l,hw] = sum_c f[c,hw]*pw[l,c]
__global__ __launch_bounds__(256) void k_sa_dot(
    const float* __restrict__ fp1, const float* __restrict__ fp2,
    const float* __restrict__ cw1, const float* __restrict__ cw2,
    const float* __restrict__ pw1, const float* __restrict__ pw2,
    float* __restrict__ cval, float* __restrict__ pdot)
{
  const int n = blockIdx.z, side = blockIdx.y, hw0 = blockIdx.x * 64;
  const int t = threadIdx.x, hwl = t & 63, cg = t >> 6;
  const float* __restrict__ pw = side ? pw2 : pw1;
  const float* __restrict__ cw = side ? cw2 : cw1;
  const float* __restrict__ f  = (side ? fp2 : fp1) + (size_t)n * C_ * HW_ + hw0 + hwl;
  const int cb = __builtin_amdgcn_readfirstlane(cg * 64);

  float acc[17];
  #pragma unroll
  for (int l = 0; l < 17; ++l) acc[l] = 0.f;

  for (int cc = 0; cc < 64; ++cc){
    const int c = cb + cc;
    const float v = f[(size_t)c * HW_];
    acc[16] += v * cw[c];
    #pragma unroll
    for (int l = 0; l < 16; ++l) acc[l] += v * pw[l * C_ + c];
  }

  __shared__ float red[17][4][64];
  #pragma unroll
  for (int l = 0; l < 17; ++l) red[l][cg][hwl] = acc[l];
  __syncthreads();

  if (t < 64){
    const int base = n * 2 + side;
    #pragma unroll
    for (int l = 0; l < 17; ++l){
      const float s = red[l][0][t] + red[l][1][t] + red[l][2][t] + red[l][3][t];
      if (l < 16) pdot[((size_t)base * CL_ + l) * HW_ + hw0 + t] = s;
      else        cval[(size_t)base * HW_ + hw0 + t] = s;
    }
  }
}

// K1b: softmax over HW -> wbuf; fcl = w*pdot + pb (fcl aliases pdot, same-index RMW)
__global__ __launch_bounds__(1024) void k_softmax_fcl(
    const float* __restrict__ cval, const float* __restrict__ pdot,
    const float* __restrict__ cb1, const float* __restrict__ cb2,
    const float* __restrict__ pb1, const float* __restrict__ pb2,
    float* __restrict__ wbuf, float* __restrict__ fcl)
{
  const int side = blockIdx.x, n = blockIdx.y, t = threadIdx.x;
  const int base = n * 2 + side;
  __shared__ float arr[1024];

  const float x = cval[(size_t)base * HW_ + t] + (side ? cb2[0] : cb1[0]);
  arr[t] = x; __syncthreads();
  for (int s = 512; s > 0; s >>= 1){ if (t < s) arr[t] = fmaxf(arr[t], arr[t + s]); __syncthreads(); }
  const float m = arr[0]; __syncthreads();

  const float e = __expf(x - m);
  arr[t] = e; __syncthreads();
  for (int s = 512; s > 0; s >>= 1){ if (t < s) arr[t] += arr[t + s]; __syncthreads(); }
  const float wv = e / arr[0];

  wbuf[(size_t)base * HW_ + t] = wv;
  const float* __restrict__ pb = side ? pb2 : pb1;
  #pragma unroll
  for (int l = 0; l < 16; ++l){
    const size_t pi = ((size_t)base * CL_ + l) * HW_ + t;
    fcl[pi] = wv * pdot[pi] + pb[l];
  }
}

// K_xw: Xw[side][n][c][hw] (bf16) = w[n,side,hw] * f[n,c,hw]
__global__ __launch_bounds__(256) void k_xw(
    const float* __restrict__ fp1, const float* __restrict__ fp2,
    const float* __restrict__ wbuf,
    unsigned short* __restrict__ xw1, unsigned short* __restrict__ xw2)
{
  const int side = blockIdx.y;
  const size_t o = ((size_t)blockIdx.x * 256 + threadIdx.x) * 8;
  const float* __restrict__ f = side ? fp2 : fp1;
  unsigned short* __restrict__ xw = side ? xw2 : xw1;
  const int n = (int)(o >> 18), hw = (int)(o & (HW_ - 1));
  const float4 v0 = *(const float4*)&f[o];
  const float4 v1 = *(const float4*)&f[o + 4];
  const float* wp = &wbuf[(size_t)(n * 2 + side) * HW_ + hw];
  const float4 w0 = *(const float4*)wp;
  const float4 w1 = *(const float4*)(wp + 4);
  short8v r;
  r[0] = (short)f2bf(v0.x * w0.x); r[1] = (short)f2bf(v0.y * w0.y);
  r[2] = (short)f2bf(v0.z * w0.z); r[3] = (short)f2bf(v0.w * w0.w);
  r[4] = (short)f2bf(v1.x * w1.x); r[5] = (short)f2bf(v1.y * w1.y);
  r[6] = (short)f2bf(v1.z * w1.z); r[7] = (short)f2bf(v1.w * w1.w);
  *(short8v*)&xw[o] = r;
}

// K2: A[n,i,j] = tanh( sum_l f2cl[l,i] * f1cl[l,j] ), writes bf16 A and A^T
__global__ __launch_bounds__(256) void k_corr(
    const float* __restrict__ fcl,
    unsigned short* __restrict__ Abf, unsigned short* __restrict__ Atbf)
{
  const int n = blockIdx.z, i0 = blockIdx.y * 64, j0 = blockIdx.x * 64;
  const float* __restrict__ f1c = fcl + (size_t)(n * 2 + 0) * CL_ * HW_;
  const float* __restrict__ f2c = fcl + (size_t)(n * 2 + 1) * CL_ * HW_;
  __align__(16) __shared__ float s2[CL_][64];
  __align__(16) __shared__ float s1[CL_][64];
  const int t = threadIdx.x;
  const int lr = t >> 4, lc = (t & 15) * 4;
  *(float4*)&s2[lr][lc] = *(const float4*)&f2c[(size_t)lr * HW_ + i0 + lc];
  *(float4*)&s1[lr][lc] = *(const float4*)&f1c[(size_t)lr * HW_ + j0 + lc];
  __syncthreads();

  const int ti = t >> 4, tj = t & 15;
  float acc[4][4];
  #pragma unroll
  for (int a = 0; a < 4; ++a)
    #pragma unroll
    for (int b = 0; b < 4; ++b) acc[a][b] = 0.f;

  #pragma unroll
  for (int l = 0; l < CL_; ++l){
    const float4 a4 = *(const float4*)&s2[l][ti * 4];
    const float4 b4 = *(const float4*)&s1[l][tj * 4];
    const float av[4] = {a4.x, a4.y, a4.z, a4.w};
    const float bv[4] = {b4.x, b4.y, b4.z, b4.w};
    #pragma unroll
    for (int a = 0; a < 4; ++a)
      #pragma unroll
      for (int b = 0; b < 4; ++b) acc[a][b] += av[a] * bv[b];
  }

  unsigned short tv[4][4];
  #pragma unroll
  for (int a = 0; a < 4; ++a)
    #pragma unroll
    for (int b = 0; b < 4; ++b) tv[a][b] = f2bf(tanh_fast(acc[a][b]));

  unsigned short* __restrict__ An  = Abf  + ((size_t)n << 20);
  unsigned short* __restrict__ Atn = Atbf + ((size_t)n << 20);
  #pragma unroll
  for (int a = 0; a < 4; ++a){
    ushort4 va; va.x = tv[a][0]; va.y = tv[a][1]; va.z = tv[a][2]; va.w = tv[a][3];
    *(ushort4*)&An[(size_t)(i0 + ti * 4 + a) * HW_ + j0 + tj * 4] = va;
  }
  #pragma unroll
  for (int b = 0; b < 4; ++b){
    ushort4 vb; vb.x = tv[0][b]; vb.y = tv[1][b]; vb.z = tv[2][b]; vb.w = tv[3][b];
    *(ushort4*)&Atn[(size_t)(j0 + tj * 4 + b) * HW_ + i0 + ti * 4] = vb;
  }
}

// K3: MFMA GEMM. g=0: hat1[c,i] = sum_j Xw1[c,j]*A[i,j]   (B^T storage = A row-major)
//                g=1: hat2[c,i] = sum_j Xw2[c,j]*A[j,i]   (B^T storage = At row-major)
// Tile BM=128(c) x BN=64(i) x BK=64(j). 256 thr / 4 waves (2x2). Wave tile 64x32.
__global__ __launch_bounds__(256) void k_gemm_mfma(
    const unsigned short* __restrict__ xw1, const unsigned short* __restrict__ xw2,
    const unsigned short* __restrict__ Abf, const unsigned short* __restrict__ Atbf,
    float* __restrict__ out)
{
  const int n = blockIdx.z, g = blockIdx.y, tile = blockIdx.x;
  const int c0 = (tile >> 4) * 128, i0 = (tile & 15) * 64;
  const unsigned short* __restrict__ X = (g ? xw2 : xw1) + (size_t)n * C_ * HW_;
  const unsigned short* __restrict__ B = (g ? Atbf : Abf) + ((size_t)n << 20);
  float* __restrict__ outp = out + (size_t)g * SZ_ + (size_t)n * C_ * HW_;

  __shared__ unsigned short Xs[128 * 64];  // 16 KB, rows of 64 bf16, XOR-swizzled chunks
  __shared__ unsigned short Bs[64 * 64];   // 8 KB

  const int t = threadIdx.x, w = t >> 6, l = t & 63;
  const int wr = w >> 1, wc = w & 1;

  f32x4 acc[4][2];
  #pragma unroll
  for (int fm = 0; fm < 4; ++fm)
    #pragma unroll
    for (int fn = 0; fn < 2; ++fn)
      acc[fm][fn] = (f32x4){0.f, 0.f, 0.f, 0.f};

  for (int k0 = 0; k0 < HW_; k0 += 64){
    // stage Xs: 1024 chunks of 16B; wave w handles insts w*4..w*4+3 (1KB each)
    #pragma unroll
    for (int s = 0; s < 4; ++s){
      const int q = (w * 4 + s) * 64 + l;
      const int row = q >> 3;
      const int kc = (q & 7) ^ (row & 7);            // pre-swizzled global source
      GLD16(X + (size_t)(c0 + row) * HW_ + k0 + kc * 8, &Xs[(w * 4 + s) * 512]);
    }
    // stage Bs: 512 chunks
    #pragma unroll
    for (int s = 0; s < 2; ++s){
      const int q = (w * 2 + s) * 64 + l;
      const int row = q >> 3;
      const int kc = (q & 7) ^ (row & 7);
      GLD16(B + (size_t)(i0 + row) * HW_ + k0 + kc * 8, &Bs[(w * 2 + s) * 512]);
    }
    __syncthreads();

    #pragma unroll
    for (int ks = 0; ks < 2; ++ks){
      short8v a[4], b[2];
      #pragma unroll
      for (int fm = 0; fm < 4; ++fm){
        const int row = wr * 64 + fm * 16 + (l & 15);
        const int kc = (ks * 4 + (l >> 4)) ^ (row & 7);  // swizzled read
        a[fm] = *(const short8v*)&Xs[row * 64 + kc * 8];
      }
      #pragma unroll
      for (int fn = 0; fn < 2; ++fn){
        const int row = wc * 32 + fn * 16 + (l & 15);
        const int kc = (ks * 4 + (l >> 4)) ^ (row & 7);
        b[fn] = *(const short8v*)&Bs[row * 64 + kc * 8];
      }
      #pragma unroll
      for (int fm = 0; fm < 4; ++fm)
        #pragma unroll
        for (int fn = 0; fn < 2; ++fn)
          acc[fm][fn] = __builtin_amdgcn_mfma_f32_16x16x32_bf16(a[fm], b[fn], acc[fm][fn], 0, 0, 0);
    }
    __syncthreads();
  }

  // epilogue: C/D layout col=lane&15, row=(lane>>4)*4+reg
  const int rbase = (l >> 4) * 4, col = l & 15;
  #pragma unroll
  for (int fm = 0; fm < 4; ++fm)
    #pragma unroll
    for (int fn = 0; fn < 2; ++fn){
      float* op = outp + (size_t)(c0 + wr * 64 + fm * 16 + rbase) * HW_ + i0 + wc * 32 + fn * 16 + col;
      #pragma unroll
      for (int r = 0; r < 4; ++r) op[(size_t)r * HW_] = acc[fm][fn][r];
    }
}

// K4: h = hat / max(||hat||_c, eps); fp = relu(h + fp_in) unless last
__global__ __launch_bounds__(256) void k_norm_update(
    float* __restrict__ out,
    const float* __restrict__ fpin1, const float* __restrict__ fpin2,
    float* __restrict__ fpo1, float* __restrict__ fpo2, int last)
{
  const int n = blockIdx.z, side = blockIdx.y, i0 = blockIdx.x * 64;
  float* __restrict__ hat = out + (size_t)side * SZ_ + (size_t)n * C_ * HW_;
  const float* __restrict__ fpin = (side ? fpin2 : fpin1) + (size_t)n * C_ * HW_;
  float* __restrict__ fpo = (side ? fpo2 : fpo1) + (size_t)n * C_ * HW_;
  const int t = threadIdx.x, il = t & 63, cg = t >> 6;

  float ss = 0.f;
  for (int cc = 0; cc < 64; ++cc){
    const float v = hat[(size_t)(cg * 64 + cc) * HW_ + i0 + il];
    ss += v * v;
  }
  __shared__ float red[4][64];
  __shared__ float rinv[64];
  red[cg][il] = ss; __syncthreads();
  if (t < 64){
    const float s = red[0][t] + red[1][t] + red[2][t] + red[3][t];
    rinv[t] = 1.f / fmaxf(sqrtf(s), 1e-12f);
  }
  __syncthreads();
  const float ri = rinv[il];

  for (int cc = 0; cc < 64; ++cc){
    const size_t idx = (size_t)(cg * 64 + cc) * HW_ + i0 + il;
    const float h = hat[idx] * ri;
    hat[idx] = h;
    if (!last){
      const float fv = fpin[idx] + h;
      fpo[idx] = fv > 0.f ? fv : 0.f;
    }
  }
}

// K_s: s[n,c,hw] = w[n,side,hw] * fp[n,c,hw]
__global__ __launch_bounds__(256) void k_s_out(
    const float* __restrict__ fp1, const float* __restrict__ fp2,
    const float* __restrict__ wbuf, float* __restrict__ out)
{
  const int side = blockIdx.y;
  const size_t fo = ((size_t)blockIdx.x * 256 + threadIdx.x) * 4;
  const float* __restrict__ f = side ? fp2 : fp1;
  const int n  = (int)(fo >> 18);
  const int hw = (int)(fo & (HW_ - 1));
  const float4 v  = *(const float4*)&f[fo];
  const float4 wv = *(const float4*)&wbuf[(size_t)(n * 2 + side) * HW_ + hw];
  float4 r;
  r.x = v.x * wv.x; r.y = v.y * wv.y; r.z = v.z * wv.z; r.w = v.w * wv.w;
  *(float4*)&out[(size_t)(2 + side) * SZ_ + fo] = r;
}

extern "C" void kernel_launch(void* const* d_in, const int* in_sizes, int n_in,
                              void* d_out, int out_size, void* d_ws, size_t ws_size,
                              hipStream_t stream)
{
  const float* f1  = (const float*)d_in[0];
  const float* f2  = (const float*)d_in[1];
  const float* pw1 = (const float*)d_in[2];
  const float* pb1 = (const float*)d_in[3];
  const float* pw2 = (const float*)d_in[4];
  const float* pb2 = (const float*)d_in[5];
  const float* cw1 = (const float*)d_in[6];
  const float* cb1 = (const float*)d_in[7];
  const float* cw2 = (const float*)d_in[8];
  const float* cb2 = (const float*)d_in[9];
  float* out = (float*)d_out;
  float* ws  = (float*)d_ws;

  // workspace layout
  float* fp1  = ws;                          // SZ_ f32
  float* fp2  = fp1  + SZ_;                  // SZ_ f32
  float* cval = fp2  + SZ_;                  // 16K f32
  float* wbuf = cval + N_ * 2 * HW_;         // 16K f32
  float* pdot = wbuf + N_ * 2 * HW_;         // 256K f32 (fcl aliases pdot)
  unsigned short* xw1  = (unsigned short*)(pdot + N_ * 2 * CL_ * HW_); // SZ_ bf16
  unsigned short* xw2  = xw1 + SZ_;                                    // SZ_ bf16
  unsigned short* Abf  = xw2 + SZ_;                                    // 8M bf16
  unsigned short* Atbf = Abf + ((size_t)N_ << 20);                     // 8M bf16

  for (int it = 0; it < 5; ++it){
    const float* cur1 = (it == 0) ? f1 : fp1;
    const float* cur2 = (it == 0) ? f2 : fp2;

    k_sa_dot<<<dim3(16, 2, 8), 256, 0, stream>>>(cur1, cur2, cw1, cw2, pw1, pw2, cval, pdot);
    k_softmax_fcl<<<dim3(2, 8), 1024, 0, stream>>>(cval, pdot, cb1, cb2, pb1, pb2, wbuf, pdot);
    k_xw<<<dim3(SZ_ / 8 / 256, 2), 256, 0, stream>>>(cur1, cur2, wbuf, xw1, xw2);
    if (it == 4)
      k_s_out<<<dim3(SZ_ / 4 / 256, 2), 256, 0, stream>>>(cur1, cur2, wbuf, out);
    k_corr<<<dim3(16, 16, 8), 256, 0, stream>>>(pdot, Abf, Atbf);
    k_gemm_mfma<<<dim3(32, 2, 8), 256, 0, stream>>>(xw1, xw2, Abf, Atbf, out);
    k_norm_update<<<dim3(16, 2, 8), 256, 0, stream>>>(out, cur1, cur2, fp1, fp2, (it == 4) ? 1 : 0);
  }
}

// Round 3
// 310.606 us; speedup vs baseline: 3.1841x; 1.2147x over previous
//
#include <hip/hip_runtime.h>
#include <cstdint>
#include <cstddef>

#define N_  8
#define C_  256
#define HW_ 1024
#define CL_ 16
#define SZ_ (N_*C_*HW_)   // 2,097,152 elements per tensor

typedef __attribute__((ext_vector_type(8))) _Float16 half8;
typedef __attribute__((ext_vector_type(4))) float f32x4;

static __device__ __forceinline__ float tanh_fast(float x){
  x = fminf(fmaxf(x, -15.f), 15.f);
  float e = __expf(2.f * x);
  return (e - 1.f) / (e + 1.f);
}

static __device__ __forceinline__ unsigned short f2h(float x){
  _Float16 h = (_Float16)x;
  return *(unsigned short*)&h;
}

#define GLD16(g, l) __builtin_amdgcn_global_load_lds( \
    (const __attribute__((address_space(1))) void*)(g), \
    (__attribute__((address_space(3))) void*)(l), 16, 0, 0)

// K1: cval[n,side,hw] = sum_c f[c,hw]*cw[c];  pdot[n,side,l,hw] = sum_c f[c,hw]*pw[l,c]
//     + per-block online-softmax partials (max, sumexp) of cval
__global__ __launch_bounds__(256) void k_sa_dot(
    const float* __restrict__ fp1, const float* __restrict__ fp2,
    const float* __restrict__ cw1, const float* __restrict__ cw2,
    const float* __restrict__ pw1, const float* __restrict__ pw2,
    float* __restrict__ cval, float* __restrict__ pdot,
    float* __restrict__ mpart, float* __restrict__ spart)
{
  const int n = blockIdx.z, side = blockIdx.y, hw0 = blockIdx.x * 64;
  const int t = threadIdx.x, hwl = t & 63, cg = t >> 6;
  const float* __restrict__ pw = side ? pw2 : pw1;
  const float* __restrict__ cw = side ? cw2 : cw1;
  const float* __restrict__ f  = (side ? fp2 : fp1) + (size_t)n * C_ * HW_ + hw0 + hwl;
  const int cb = __builtin_amdgcn_readfirstlane(cg * 64);

  float acc[17];
  #pragma unroll
  for (int l = 0; l < 17; ++l) acc[l] = 0.f;

  for (int cc = 0; cc < 64; ++cc){
    const int c = cb + cc;
    const float v = f[(size_t)c * HW_];
    acc[16] += v * cw[c];
    #pragma unroll
    for (int l = 0; l < 16; ++l) acc[l] += v * pw[l * C_ + c];
  }

  __shared__ float red[17][4][64];
  #pragma unroll
  for (int l = 0; l < 17; ++l) red[l][cg][hwl] = acc[l];
  __syncthreads();

  if (t < 64){
    const int base = n * 2 + side;
    float xc = 0.f;
    #pragma unroll
    for (int l = 0; l < 17; ++l){
      const float s = red[l][0][t] + red[l][1][t] + red[l][2][t] + red[l][3][t];
      if (l < 16) pdot[((size_t)base * CL_ + l) * HW_ + hw0 + t] = s;
      else      { cval[(size_t)base * HW_ + hw0 + t] = s; xc = s; }
    }
    // wave-0 reduce: block max + sumexp over the 64 cval values
    float mb = xc;
    #pragma unroll
    for (int off = 32; off; off >>= 1) mb = fmaxf(mb, __shfl_xor(mb, off));
    float e = __expf(xc - mb);
    #pragma unroll
    for (int off = 32; off; off >>= 1) e += __shfl_xor(e, off);
    if (t == 0){
      mpart[base * 16 + blockIdx.x] = mb;
      spart[base * 16 + blockIdx.x] = e;
    }
  }
}

// K1c: combine 16 partials per (n,side) -> mrow (global max), rlrow (1/sumexp)
__global__ __launch_bounds__(64) void k_combine(
    const float* __restrict__ mpart, const float* __restrict__ spart,
    float* __restrict__ mrow, float* __restrict__ rlrow)
{
  const int t = threadIdx.x;
  if (t < 32){
    float m = -1e30f;
    #pragma unroll
    for (int k = 0; k < 16; ++k) m = fmaxf(m, mpart[t * 16 + k]);
    float s = 0.f;
    #pragma unroll
    for (int k = 0; k < 16; ++k) s += spart[t * 16 + k] * __expf(mpart[t * 16 + k] - m);
    mrow[t] = m;
    rlrow[t] = 1.f / s;
  }
}

// K_xw: Xw (fp16) = w * f,  w = exp(cval - m) * rl
__global__ __launch_bounds__(256) void k_xw(
    const float* __restrict__ fp1, const float* __restrict__ fp2,
    const float* __restrict__ cval,
    const float* __restrict__ mrow, const float* __restrict__ rlrow,
    unsigned short* __restrict__ xw1, unsigned short* __restrict__ xw2)
{
  const int side = blockIdx.y;
  const size_t o = ((size_t)blockIdx.x * 256 + threadIdx.x) * 8;
  const float* __restrict__ f = side ? fp2 : fp1;
  unsigned short* __restrict__ xw = side ? xw2 : xw1;
  const int n = (int)(o >> 18), hw = (int)(o & (HW_ - 1));
  const int base = n * 2 + side;
  const float m = mrow[base], rl = rlrow[base];
  const float* cp = &cval[(size_t)base * HW_ + hw];
  const float4 c0 = *(const float4*)cp;
  const float4 c1 = *(const float4*)(cp + 4);
  const float4 v0 = *(const float4*)&f[o];
  const float4 v1 = *(const float4*)&f[o + 4];
  half8 r;
  r[0] = (_Float16)(v0.x * (__expf(c0.x - m) * rl));
  r[1] = (_Float16)(v0.y * (__expf(c0.y - m) * rl));
  r[2] = (_Float16)(v0.z * (__expf(c0.z - m) * rl));
  r[3] = (_Float16)(v0.w * (__expf(c0.w - m) * rl));
  r[4] = (_Float16)(v1.x * (__expf(c1.x - m) * rl));
  r[5] = (_Float16)(v1.y * (__expf(c1.y - m) * rl));
  r[6] = (_Float16)(v1.z * (__expf(c1.z - m) * rl));
  r[7] = (_Float16)(v1.w * (__expf(c1.w - m) * rl));
  *(half8*)&xw[o] = r;
}

// K2: A[n,i,j] = tanh( sum_l fcl2[l,i] * fcl1[l,j] ), fcl = w*pdot + pb computed inline.
//     Writes fp16 A and A^T.
__global__ __launch_bounds__(256) void k_corr(
    const float* __restrict__ cval, const float* __restrict__ pdot,
    const float* __restrict__ pb1, const float* __restrict__ pb2,
    const float* __restrict__ mrow, const float* __restrict__ rlrow,
    unsigned short* __restrict__ Abf, unsigned short* __restrict__ Atbf)
{
  const int n = blockIdx.z, i0 = blockIdx.y * 64, j0 = blockIdx.x * 64;
  const int b1 = n * 2, b2 = n * 2 + 1;
  __align__(16) __shared__ float s2[CL_][64];
  __align__(16) __shared__ float s1[CL_][64];
  const int t = threadIdx.x;
  const int lr = t >> 4, lc = (t & 15) * 4;

  {
    const float m2 = mrow[b2], rl2 = rlrow[b2], bias2 = pb2[lr];
    const float4 c2 = *(const float4*)&cval[(size_t)b2 * HW_ + i0 + lc];
    const float4 p2 = *(const float4*)&pdot[((size_t)b2 * CL_ + lr) * HW_ + i0 + lc];
    s2[lr][lc + 0] = __expf(c2.x - m2) * rl2 * p2.x + bias2;
    s2[lr][lc + 1] = __expf(c2.y - m2) * rl2 * p2.y + bias2;
    s2[lr][lc + 2] = __expf(c2.z - m2) * rl2 * p2.z + bias2;
    s2[lr][lc + 3] = __expf(c2.w - m2) * rl2 * p2.w + bias2;

    const float m1 = mrow[b1], rl1 = rlrow[b1], bias1 = pb1[lr];
    const float4 c1 = *(const float4*)&cval[(size_t)b1 * HW_ + j0 + lc];
    const float4 p1 = *(const float4*)&pdot[((size_t)b1 * CL_ + lr) * HW_ + j0 + lc];
    s1[lr][lc + 0] = __expf(c1.x - m1) * rl1 * p1.x + bias1;
    s1[lr][lc + 1] = __expf(c1.y - m1) * rl1 * p1.y + bias1;
    s1[lr][lc + 2] = __expf(c1.z - m1) * rl1 * p1.z + bias1;
    s1[lr][lc + 3] = __expf(c1.w - m1) * rl1 * p1.w + bias1;
  }
  __syncthreads();

  const int ti = t >> 4, tj = t & 15;
  float acc[4][4];
  #pragma unroll
  for (int a = 0; a < 4; ++a)
    #pragma unroll
    for (int b = 0; b < 4; ++b) acc[a][b] = 0.f;

  #pragma unroll
  for (int l = 0; l < CL_; ++l){
    const float4 a4 = *(const float4*)&s2[l][ti * 4];
    const float4 b4 = *(const float4*)&s1[l][tj * 4];
    const float av[4] = {a4.x, a4.y, a4.z, a4.w};
    const float bv[4] = {b4.x, b4.y, b4.z, b4.w};
    #pragma unroll
    for (int a = 0; a < 4; ++a)
      #pragma unroll
      for (int b = 0; b < 4; ++b) acc[a][b] += av[a] * bv[b];
  }

  unsigned short tv[4][4];
  #pragma unroll
  for (int a = 0; a < 4; ++a)
    #pragma unroll
    for (int b = 0; b < 4; ++b) tv[a][b] = f2h(tanh_fast(acc[a][b]));

  unsigned short* __restrict__ An  = Abf  + ((size_t)n << 20);
  unsigned short* __restrict__ Atn = Atbf + ((size_t)n << 20);
  #pragma unroll
  for (int a = 0; a < 4; ++a){
    ushort4 va; va.x = tv[a][0]; va.y = tv[a][1]; va.z = tv[a][2]; va.w = tv[a][3];
    *(ushort4*)&An[(size_t)(i0 + ti * 4 + a) * HW_ + j0 + tj * 4] = va;
  }
  #pragma unroll
  for (int b = 0; b < 4; ++b){
    ushort4 vb; vb.x = tv[0][b]; vb.y = tv[1][b]; vb.z = tv[2][b]; vb.w = tv[3][b];
    *(ushort4*)&Atn[(size_t)(j0 + tj * 4 + b) * HW_ + i0 + ti * 4] = vb;
  }
}

// K3: fused MFMA GEMM + channel-L2-norm + residual/ReLU.
// g=0: hat1[c,i] = sum_j Xw1[c,j]*A[i,j];  g=1: hat2[c,i] = sum_j Xw2[c,j]*A[j,i]
// BM=256 (all of C) x BN=64 x BK=64, 512 thr / 8 waves (4 row x 2 col), wave tile 64x32.
// Double-buffered LDS, one barrier per K-step; XOR-swizzled (pre-swizzled global src).
__global__ __launch_bounds__(512) void k_gemm_fused(
    const unsigned short* __restrict__ xw1, const unsigned short* __restrict__ xw2,
    const unsigned short* __restrict__ Abf, const unsigned short* __restrict__ Atbf,
    const float* __restrict__ fpin1, const float* __restrict__ fpin2,
    float* __restrict__ fpo1, float* __restrict__ fpo2,
    float* __restrict__ out, int last)
{
  const int n = blockIdx.z, g = blockIdx.y, i0 = blockIdx.x * 64;
  const unsigned short* __restrict__ X = (g ? xw2 : xw1) + (size_t)n * C_ * HW_;
  const unsigned short* __restrict__ B = (g ? Atbf : Abf) + ((size_t)n << 20);

  __shared__ unsigned short Xs[2][256 * 64];  // 2 x 32 KB
  __shared__ unsigned short Bs[2][64 * 64];   // 2 x 8 KB
  __shared__ float ssred[4][64];
  __shared__ float rinv[64];

  const int t = threadIdx.x, w = t >> 6, l = t & 63;
  const int wr = w >> 1, wc = w & 1;

  f32x4 acc[4][2];
  #pragma unroll
  for (int fm = 0; fm < 4; ++fm)
    #pragma unroll
    for (int fn = 0; fn < 2; ++fn)
      acc[fm][fn] = (f32x4){0.f, 0.f, 0.f, 0.f};

  auto stage = [&](int buf, int k0){
    #pragma unroll
    for (int s = 0; s < 4; ++s){
      const int q = (w * 4 + s) * 64 + l;
      const int row = q >> 3;
      const int kc = (q & 7) ^ (row & 7);
      GLD16(X + (size_t)row * HW_ + k0 + kc * 8, &Xs[buf][(w * 4 + s) * 512]);
    }
    {
      const int q = w * 64 + l;
      const int row = q >> 3;
      const int kc = (q & 7) ^ (row & 7);
      GLD16(B + (size_t)(i0 + row) * HW_ + k0 + kc * 8, &Bs[buf][w * 512]);
    }
  };

  stage(0, 0);
  __syncthreads();
  int cur = 0;
  for (int kt = 0; kt < 16; ++kt){
    if (kt < 15) stage(cur ^ 1, (kt + 1) * 64);
    #pragma unroll
    for (int ks = 0; ks < 2; ++ks){
      half8 a[4], b[2];
      #pragma unroll
      for (int fm = 0; fm < 4; ++fm){
        const int row = wr * 64 + fm * 16 + (l & 15);
        const int kc = (ks * 4 + (l >> 4)) ^ (row & 7);
        a[fm] = *(const half8*)&Xs[cur][row * 64 + kc * 8];
      }
      #pragma unroll
      for (int fn = 0; fn < 2; ++fn){
        const int row = wc * 32 + fn * 16 + (l & 15);
        const int kc = (ks * 4 + (l >> 4)) ^ (row & 7);
        b[fn] = *(const half8*)&Bs[cur][row * 64 + kc * 8];
      }
      #pragma unroll
      for (int fm = 0; fm < 4; ++fm)
        #pragma unroll
        for (int fn = 0; fn < 2; ++fn)
          acc[fm][fn] = __builtin_amdgcn_mfma_f32_16x16x32_f16(a[fm], b[fn], acc[fm][fn], 0, 0, 0);
    }
    __syncthreads();
    cur ^= 1;
  }

  // --- fused epilogue: column L2 norm over all 256 channels, then resid/relu or out ---
  float ss0 = 0.f, ss1 = 0.f;
  #pragma unroll
  for (int fm = 0; fm < 4; ++fm)
    #pragma unroll
    for (int r = 0; r < 4; ++r){
      ss0 += acc[fm][0][r] * acc[fm][0][r];
      ss1 += acc[fm][1][r] * acc[fm][1][r];
    }
  ss0 += __shfl_xor(ss0, 16); ss0 += __shfl_xor(ss0, 32);
  ss1 += __shfl_xor(ss1, 16); ss1 += __shfl_xor(ss1, 32);
  if (l < 16){
    ssred[wr][wc * 32 + l]      = ss0;
    ssred[wr][wc * 32 + 16 + l] = ss1;
  }
  __syncthreads();
  if (t < 64)
    rinv[t] = 1.f / fmaxf(sqrtf(ssred[0][t] + ssred[1][t] + ssred[2][t] + ssred[3][t]), 1e-12f);
  __syncthreads();

  const float ri[2] = { rinv[wc * 32 + (l & 15)], rinv[wc * 32 + 16 + (l & 15)] };

  const float* __restrict__ fpin = (g ? fpin2 : fpin1) + (size_t)n * C_ * HW_;
  float* __restrict__ fpo  = (g ? fpo2 : fpo1) + (size_t)n * C_ * HW_;
  float* __restrict__ outp = out + (size_t)g * SZ_ + (size_t)n * C_ * HW_;
  const int rbase = (l >> 4) * 4, col = l & 15;

  #pragma unroll
  for (int fm = 0; fm < 4; ++fm)
    #pragma unroll
    for (int fn = 0; fn < 2; ++fn){
      const size_t base = (size_t)(wr * 64 + fm * 16 + rbase) * HW_ + i0 + wc * 32 + fn * 16 + col;
      #pragma unroll
      for (int r = 0; r < 4; ++r){
        const float h = acc[fm][fn][r] * ri[fn];
        if (last) outp[base + (size_t)r * HW_] = h;
        else {
          const float fv = fpin[base + (size_t)r * HW_] + h;
          fpo[base + (size_t)r * HW_] = fv > 0.f ? fv : 0.f;
        }
      }
    }
}

// K_s: s[n,c,hw] = w * fp,  w = exp(cval - m) * rl
__global__ __launch_bounds__(256) void k_s_out(
    const float* __restrict__ fp1, const float* __restrict__ fp2,
    const float* __restrict__ cval,
    const float* __restrict__ mrow, const float* __restrict__ rlrow,
    float* __restrict__ out)
{
  const int side = blockIdx.y;
  const size_t fo = ((size_t)blockIdx.x * 256 + threadIdx.x) * 4;
  const float* __restrict__ f = side ? fp2 : fp1;
  const int n  = (int)(fo >> 18);
  const int hw = (int)(fo & (HW_ - 1));
  const int base = n * 2 + side;
  const float m = mrow[base], rl = rlrow[base];
  const float4 c = *(const float4*)&cval[(size_t)base * HW_ + hw];
  const float4 v = *(const float4*)&f[fo];
  float4 r;
  r.x = v.x * (__expf(c.x - m) * rl);
  r.y = v.y * (__expf(c.y - m) * rl);
  r.z = v.z * (__expf(c.z - m) * rl);
  r.w = v.w * (__expf(c.w - m) * rl);
  *(float4*)&out[(size_t)(2 + side) * SZ_ + fo] = r;
}

extern "C" void kernel_launch(void* const* d_in, const int* in_sizes, int n_in,
                              void* d_out, int out_size, void* d_ws, size_t ws_size,
                              hipStream_t stream)
{
  const float* f1  = (const float*)d_in[0];
  const float* f2  = (const float*)d_in[1];
  const float* pw1 = (const float*)d_in[2];
  const float* pb1 = (const float*)d_in[3];
  const float* pw2 = (const float*)d_in[4];
  const float* pb2 = (const float*)d_in[5];
  const float* cw1 = (const float*)d_in[6];
  const float* cw2 = (const float*)d_in[8];
  // cb1/cb2 unused: softmax is shift-invariant
  float* out = (float*)d_out;
  float* ws  = (float*)d_ws;

  float* fp1   = ws;                           // SZ_ f32
  float* fp2   = fp1  + SZ_;                   // SZ_ f32
  float* cval  = fp2  + SZ_;                   // 16K f32
  float* pdot  = cval + N_ * 2 * HW_;          // 256K f32
  float* mpart = pdot + N_ * 2 * CL_ * HW_;    // 512
  float* spart = mpart + 512;                  // 512
  float* mrow  = spart + 512;                  // 32
  float* rlrow = mrow + 32;                    // 32
  unsigned short* xw1  = (unsigned short*)(rlrow + 32);  // SZ_ fp16
  unsigned short* xw2  = xw1 + SZ_;                      // SZ_ fp16
  unsigned short* Abf  = xw2 + SZ_;                      // 8M fp16
  unsigned short* Atbf = Abf + ((size_t)N_ << 20);       // 8M fp16

  for (int it = 0; it < 5; ++it){
    const float* cur1 = (it == 0) ? f1 : fp1;
    const float* cur2 = (it == 0) ? f2 : fp2;

    k_sa_dot<<<dim3(16, 2, 8), 256, 0, stream>>>(cur1, cur2, cw1, cw2, pw1, pw2,
                                                 cval, pdot, mpart, spart);
    k_combine<<<dim3(1), 64, 0, stream>>>(mpart, spart, mrow, rlrow);
    k_xw<<<dim3(SZ_ / 8 / 256, 2), 256, 0, stream>>>(cur1, cur2, cval, mrow, rlrow, xw1, xw2);
    if (it == 4)
      k_s_out<<<dim3(SZ_ / 4 / 256, 2), 256, 0, stream>>>(cur1, cur2, cval, mrow, rlrow, out);
    k_corr<<<dim3(16, 16, 8), 256, 0, stream>>>(cval, pdot, pb1, pb2, mrow, rlrow, Abf, Atbf);
    k_gemm_fused<<<dim3(16, 2, 8), 512, 0, stream>>>(xw1, xw2, Abf, Atbf,
                                                     cur1, cur2, fp1, fp2, out, (it == 4) ? 1 : 0);
  }
}